// Round 1
// baseline (196.365 us; speedup 1.0000x reference)
//
#include <hip/hip_runtime.h>

typedef __attribute__((ext_vector_type(4))) float float4v;
typedef __attribute__((ext_vector_type(2))) float float2v;
typedef __attribute__((ext_vector_type(8))) short short8;
typedef __attribute__((ext_vector_type(4))) float f32x4;

#define NEGV (-1000000000.0f)

// B=64, L=2048, E=512, Q=256
// M = B*L = 131072, K = 512 (encoded part), N = 512

__device__ __forceinline__ unsigned short f2bf(float f) {
    unsigned int u = __float_as_uint(f);
    u += 0x7fffu + ((u >> 16) & 1u);   // RNE round to bf16
    return (unsigned short)(u >> 16);
}

// Wt[e][c] = bf16(W1[c][e]) for c,e in [0,512): transposed bf16 copy of the
// encoded-part of W1. Coalesced reads, scattered writes (1MB, L2-resident).
__global__ void prep_wt_kernel(const float* __restrict__ W1, unsigned short* __restrict__ Wt) {
    int idx = blockIdx.x * 256 + threadIdx.x;   // over 512*512
    int c = idx >> 9;
    int e = idx & 511;
    Wt[e * 512 + c] = f2bf(W1[idx]);
}

// qc[b][e] = b1[e] + sum_q query[b][q] * W1[512+q][e]   (query half of h@W1)
__global__ void prep_qc_kernel(const float* __restrict__ query, const float* __restrict__ W1,
                               const float* __restrict__ b1, float* __restrict__ qc) {
    int b = blockIdx.x;            // 64
    int e = threadIdx.x;           // 256 threads -> cols e and e+256
    float acc0 = b1[e];
    float acc1 = b1[e + 256];
    const float* w = W1 + 512 * 512;
    for (int q = 0; q < 256; ++q) {
        float qv = query[b * 256 + q];
        acc0 += qv * w[q * 512 + e];
        acc1 += qv * w[q * 512 + e + 256];
    }
    qc[b * 512 + e] = acc0;
    qc[b * 512 + e + 256] = acc1;
}

#define BM 128
#define BN 128
#define BKs 32
#define LDA 40   // 32 + 8 pad (bf16 elems) -> 80B row stride, 16B aligned, conflict-free-ish

// logits[row] += sum over this block's 128-col slice of tanh(enc@W1e + qc)*v
__global__ __launch_bounds__(256)
void gemm_logits_kernel(const float* __restrict__ A,            // encoded [M][512]
                        const unsigned short* __restrict__ Wt,  // [512 n][512 k] bf16
                        const float* __restrict__ qc,           // [64][512]
                        const float* __restrict__ v,            // [512]
                        const int* __restrict__ length,         // [64]
                        float* __restrict__ logits)             // [M], pre-zeroed
{
    int bn = blockIdx.x;      // 0..3  (N slices; adjacent in dispatch for A-tile L2 reuse)
    int bm = blockIdx.y;      // 0..1023
    int b = bm >> 4;          // 2048/128 = 16 tiles per batch
    int l0 = (bm & 15) * BM;
    if (l0 >= length[b]) return;   // fully-masked tile: logits stay 0, masked in softmax

    __shared__ unsigned short Asz[BM * LDA];
    __shared__ unsigned short Bsz[BN * LDA];

    int tid = threadIdx.x;
    int lane = tid & 63;
    int w = tid >> 6;
    int wm = w >> 1, wn = w & 1;

    long row0 = (long)bm * BM;
    int col0 = bn * BN;

    int sr = tid >> 1;            // staging row 0..127
    int sk = (tid & 1) * 16;      // staging k-half

    const float* Ag = A + (row0 + sr) * 512 + sk;
    const unsigned short* Bg = Wt + (long)(col0 + sr) * 512 + sk;

    f32x4 acc[4][4] = {};

    unsigned short* as = &Asz[sr * LDA + sk];
    unsigned short* bs = &Bsz[sr * LDA + sk];

    const int arow = wm * 64 + (lane & 15);
    const int brow = wn * 64 + (lane & 15);
    const int kcol = 8 * (lane >> 4);

    for (int k0 = 0; k0 < 512; k0 += BKs) {
        float4v a0 = *(const float4v*)(Ag);
        float4v a1 = *(const float4v*)(Ag + 4);
        float4v a2 = *(const float4v*)(Ag + 8);
        float4v a3 = *(const float4v*)(Ag + 12);
        short8 w0 = *(const short8*)(Bg);
        short8 w1 = *(const short8*)(Bg + 8);
        Ag += BKs; Bg += BKs;

        short8 p0, p1;
        p0[0] = (short)f2bf(a0[0]); p0[1] = (short)f2bf(a0[1]);
        p0[2] = (short)f2bf(a0[2]); p0[3] = (short)f2bf(a0[3]);
        p0[4] = (short)f2bf(a1[0]); p0[5] = (short)f2bf(a1[1]);
        p0[6] = (short)f2bf(a1[2]); p0[7] = (short)f2bf(a1[3]);
        p1[0] = (short)f2bf(a2[0]); p1[1] = (short)f2bf(a2[1]);
        p1[2] = (short)f2bf(a2[2]); p1[3] = (short)f2bf(a2[3]);
        p1[4] = (short)f2bf(a3[0]); p1[5] = (short)f2bf(a3[1]);
        p1[6] = (short)f2bf(a3[2]); p1[7] = (short)f2bf(a3[3]);

        *(short8*)as = p0;
        *(short8*)(as + 8) = p1;
        *(short8*)bs = w0;
        *(short8*)(bs + 8) = w1;
        __syncthreads();

        short8 af[4], bf[4];
        #pragma unroll
        for (int i = 0; i < 4; ++i) {
            af[i] = *(const short8*)&Asz[(arow + i * 16) * LDA + kcol];
            bf[i] = *(const short8*)&Bsz[(brow + i * 16) * LDA + kcol];
        }
        #pragma unroll
        for (int mi = 0; mi < 4; ++mi)
            #pragma unroll
            for (int ni = 0; ni < 4; ++ni)
                acc[mi][ni] = __builtin_amdgcn_mfma_f32_16x16x32_bf16(af[mi], bf[ni], acc[mi][ni], 0, 0, 0);
        __syncthreads();
    }

    // epilogue: u = tanh(acc + qc), partial logit = sum_n u*v[n], reduce 16 lanes, atomicAdd
    const float* qcb = qc + b * 512;
    float vcol[4], qcol[4];
    #pragma unroll
    for (int ni = 0; ni < 4; ++ni) {
        int c = col0 + wn * 64 + ni * 16 + (lane & 15);
        vcol[ni] = v[c];
        qcol[ni] = qcb[c];
    }
    int rbase = wm * 64 + 4 * (lane >> 4);
    #pragma unroll
    for (int mi = 0; mi < 4; ++mi) {
        #pragma unroll
        for (int j = 0; j < 4; ++j) {
            float s = 0.f;
            #pragma unroll
            for (int ni = 0; ni < 4; ++ni) {
                float x = acc[mi][ni][j] + qcol[ni];
                // tanh(x) = 1 - 2/(e^{2x}+1); exp->inf/0 saturates correctly
                float e2 = __expf(2.0f * x);
                float t = 1.0f - 2.0f * __builtin_amdgcn_rcpf(e2 + 1.0f);
                s += t * vcol[ni];
            }
            s += __shfl_xor(s, 1);
            s += __shfl_xor(s, 2);
            s += __shfl_xor(s, 4);
            s += __shfl_xor(s, 8);
            if ((lane & 15) == 0) {
                atomicAdd(&logits[row0 + rbase + mi * 16 + j], s);
            }
        }
    }
}

// masked softmax per batch row: att[b][l], zeros beyond length
__global__ void softmax_kernel(const float* __restrict__ logits, const int* __restrict__ length,
                               float* __restrict__ att) {
    int b = blockIdx.x;
    int len = length[b];
    int tid = threadIdx.x;     // 256
    int lane = tid & 63, wv = tid >> 6;
    const float* lg = logits + b * 2048;
    float* ab = att + b * 2048;

    float vals[8];
    float mymax = -3.402823466e38f;
    #pragma unroll
    for (int i = 0; i < 8; ++i) {
        int l = tid + i * 256;
        float x = (l < len) ? lg[l] : NEGV;
        vals[i] = x;
        mymax = fmaxf(mymax, x);
    }
    #pragma unroll
    for (int m = 32; m; m >>= 1) mymax = fmaxf(mymax, __shfl_xor(mymax, m));
    __shared__ float sm[4];
    if (lane == 0) sm[wv] = mymax;
    __syncthreads();
    float bmax = fmaxf(fmaxf(sm[0], sm[1]), fmaxf(sm[2], sm[3]));

    float mysum = 0.f;
    #pragma unroll
    for (int i = 0; i < 8; ++i) {
        int l = tid + i * 256;
        float e = (l < len) ? __expf(vals[i] - bmax) : 0.f;
        vals[i] = e;
        mysum += e;
    }
    #pragma unroll
    for (int m = 32; m; m >>= 1) mysum += __shfl_xor(mysum, m);
    __shared__ float ss[4];
    if (lane == 0) ss[wv] = mysum;
    __syncthreads();
    float tot = ss[0] + ss[1] + ss[2] + ss[3];
    float inv = 1.0f / (tot + 1e-5f);
    #pragma unroll
    for (int i = 0; i < 8; ++i) {
        int l = tid + i * 256;
        ab[l] = vals[i] * inv;
    }
}

// context[b][e] = sum_l att[b][l] * enc[b][l][e]; skip masked L-chunks (att==0)
__global__ void ctx_kernel(const float* __restrict__ att, const float* __restrict__ enc,
                           const int* __restrict__ length, float* __restrict__ ctx) {
    int b = blockIdx.x;        // 64
    int lc = blockIdx.y;       // 16 chunks of 128
    int len = length[b];
    int l0 = lc * 128;
    if (l0 >= len) return;
    int lim = len - l0;
    if (lim > 128) lim = 128;

    int t = threadIdx.x;       // 256 -> 2 cols each
    const float* ab = att + b * 2048 + l0;
    const float* eb = enc + ((long)(b * 2048 + l0)) * 512 + t * 2;
    float c0 = 0.f, c1 = 0.f;
    for (int l = 0; l < lim; ++l) {
        float a = ab[l];
        float2v e = *(const float2v*)(eb);
        eb += 512;
        c0 += a * e.x;
        c1 += a * e.y;
    }
    atomicAdd(&ctx[b * 512 + 2 * t], c0);
    atomicAdd(&ctx[b * 512 + 2 * t + 1], c1);
}

extern "C" void kernel_launch(void* const* d_in, const int* in_sizes, int n_in,
                              void* d_out, int out_size, void* d_ws, size_t ws_size,
                              hipStream_t stream) {
    const float* enc    = (const float*)d_in[0];   // [64,2048,512]
    const float* query  = (const float*)d_in[1];   // [64,256]
    const int*   length = (const int*)d_in[2];     // [64]
    const float* W1     = (const float*)d_in[3];   // [768,512]
    const float* b1     = (const float*)d_in[4];   // [512]
    const float* v      = (const float*)d_in[5];   // [512]

    float* out = (float*)d_out;
    float* ctx = out;                // [64,512]
    float* att = out + 64 * 512;     // [64,2048]

    char* ws = (char*)d_ws;
    float* logits      = (float*)ws;                              // 64*2048 f32 = 512KB
    float* qc          = (float*)(ws + 64 * 2048 * 4);            // 64*512 f32  = 128KB
    unsigned short* Wt = (unsigned short*)(ws + 64 * 2048 * 4 + 64 * 512 * 4); // 512KB

    hipMemsetAsync(logits, 0, 64 * 2048 * 4, stream);
    hipMemsetAsync(ctx, 0, 64 * 512 * 4, stream);

    prep_wt_kernel<<<(512 * 512) / 256, 256, 0, stream>>>(W1, Wt);
    prep_qc_kernel<<<64, 256, 0, stream>>>(query, W1, b1, qc);

    dim3 g1(4, 1024);   // x = N-slice (adjacent for A-tile L2 reuse), y = row tile
    gemm_logits_kernel<<<g1, 256, 0, stream>>>(enc, Wt, qc, v, length, logits);

    softmax_kernel<<<64, 256, 0, stream>>>(logits, length, att);

    dim3 g3(64, 16);
    ctx_kernel<<<g3, 256, 0, stream>>>(att, enc, length, ctx);
}

// Round 2
// 151.407 us; speedup vs baseline: 1.2969x; 1.2969x over previous
//
#include <hip/hip_runtime.h>

typedef __attribute__((ext_vector_type(4))) float float4v;
typedef __attribute__((ext_vector_type(2))) float float2v;
typedef __attribute__((ext_vector_type(8))) short short8;
typedef __attribute__((ext_vector_type(4))) float f32x4;
typedef __attribute__((ext_vector_type(4))) int int4v;

#define NEGV (-1000000000.0f)

// B=64, L=2048, E=512, Q=256; M = 131072, K = 512, N = 512

__device__ __forceinline__ unsigned short f2bf(float f) {
    unsigned int u = __float_as_uint(f);
    u += 0x7fffu + ((u >> 16) & 1u);   // RNE round to bf16
    return (unsigned short)(u >> 16);
}

// async global->LDS, 16B per lane, LDS dest = wave-uniform base + lane*16
__device__ __forceinline__ void gload_lds16(const void* g, void* l) {
    __builtin_amdgcn_global_load_lds(
        (__attribute__((address_space(1))) unsigned int*)(unsigned long long)(g),
        (__attribute__((address_space(3))) unsigned int*)(unsigned int)(unsigned long long)(l),
        16, 0, 0);
}

// Wt[e][c] = bf16(W1[c][e]): transposed bf16 copy of encoded-part of W1.
__global__ void prep_wt_kernel(const float* __restrict__ W1, unsigned short* __restrict__ Wt) {
    int idx = blockIdx.x * 256 + threadIdx.x;   // over 512*512
    int c = idx >> 9;
    int e = idx & 511;
    Wt[e * 512 + c] = f2bf(W1[idx]);
}

// qc[b][e] = b1[e] + sum_q query[b][q] * W1[512+q][e]
__global__ void prep_qc_kernel(const float* __restrict__ query, const float* __restrict__ W1,
                               const float* __restrict__ b1, float* __restrict__ qc) {
    int b = blockIdx.x;
    int e = threadIdx.x;           // 256 threads -> cols e and e+256
    float acc0 = b1[e];
    float acc1 = b1[e + 256];
    const float* w = W1 + 512 * 512;
    for (int q = 0; q < 256; ++q) {
        float qv = query[b * 256 + q];
        acc0 += qv * w[q * 512 + e];
        acc1 += qv * w[q * 512 + e + 256];
    }
    qc[b * 512 + e] = acc0;
    qc[b * 512 + e + 256] = acc1;
}

// 128x128 tile, BK=32, 4 waves, global_load_lds staging, swizzled f32 A tile.
__global__ __launch_bounds__(256)
void gemm_logits_kernel(const float* __restrict__ A,            // encoded [M][512] f32
                        const unsigned short* __restrict__ Wt,  // [512 n][512 k] bf16
                        const float* __restrict__ qc,           // [64][512]
                        const float* __restrict__ v,            // [512]
                        const int* __restrict__ length,         // [64]
                        float* __restrict__ logits)             // [M], pre-zeroed
{
    // bijective XCD swizzle: 4096 blocks, 8 XCDs, 512 per XCD; the 4 bn-slices
    // of one bm are consecutive origs -> same XCD -> A-tile L2 reuse.
    int bid = blockIdx.x;
    int orig = (bid & 7) * 512 + (bid >> 3);
    int bm = orig >> 2;        // 0..1023 row tile
    int bn = orig & 3;         // 0..3   N slice
    int b = bm >> 4;
    int l0 = (bm & 15) * 128;
    if (l0 >= length[b]) return;   // fully-masked tile

    __shared__ float As[128 * 32];           // [row][k] f32, kb XOR-swizzled by (row&7)<<4
    __shared__ unsigned short Bs[128 * 32];  // [n][k] bf16, linear (64B rows are balanced)

    int tid = threadIdx.x;
    int lane = tid & 63;
    int w = tid >> 6;
    int wm = w >> 1, wn = w & 1;
    long row0 = (long)bm * 128;
    int col0 = bn * 128;

    // --- staging addresses: LDS linear, global pre-swizzled (m173 pattern) ---
    const char* gA[4];
    const char* gB[2];
    #pragma unroll
    for (int i = 0; i < 4; ++i) {
        int off = (w * 4 + i) * 1024 + lane * 16;   // linear LDS byte
        int r = off >> 7;                            // 128B per row (32 f32)
        int kbs = off & 127;
        int kbg = kbs ^ ((r & 7) << 4);              // inverse swizzle on source
        gA[i] = (const char*)A + (row0 + r) * 2048 + kbg;
    }
    #pragma unroll
    for (int i = 0; i < 2; ++i) {
        int off = (w * 2 + i) * 1024 + lane * 16;   // 64B per row (32 bf16)
        int n = off >> 6;
        int kb = off & 63;
        gB[i] = (const char*)Wt + (long)(col0 + n) * 1024 + kb;
    }
    char* lA0 = (char*)As + (w * 4) * 1024;
    char* lB0 = (char*)Bs + (w * 2) * 1024;

    // --- fragment read byte offsets ---
    int aoff[4][2], boff[4];
    int kb0 = 32 * (lane >> 4);                      // 8 f32 per lane-group
    #pragma unroll
    for (int mi = 0; mi < 4; ++mi) {
        int ar = wm * 64 + (lane & 15) + mi * 16;
        int swz = (ar & 7) << 4;
        aoff[mi][0] = ar * 128 + (kb0 ^ swz);
        aoff[mi][1] = ar * 128 + ((kb0 + 16) ^ swz);
    }
    int kbB = 16 * (lane >> 4);                      // 8 bf16 per lane-group
    #pragma unroll
    for (int ni = 0; ni < 4; ++ni) {
        int br = wn * 64 + (lane & 15) + ni * 16;
        boff[ni] = br * 64 + kbB;
    }

    f32x4 acc[4][4] = {};

    for (int ks = 0; ks < 16; ++ks) {
        gload_lds16(gA[0], lA0);
        gload_lds16(gA[1], lA0 + 1024);
        gload_lds16(gA[2], lA0 + 2048);
        gload_lds16(gA[3], lA0 + 3072);
        gload_lds16(gB[0], lB0);
        gload_lds16(gB[1], lB0 + 1024);
        #pragma unroll
        for (int i = 0; i < 4; ++i) gA[i] += 128;
        #pragma unroll
        for (int i = 0; i < 2; ++i) gB[i] += 64;
        __syncthreads();   // compiler drains vmcnt before s_barrier

        short8 af[4], bf[4];
        #pragma unroll
        for (int mi = 0; mi < 4; ++mi) {
            float4v x = *(const float4v*)((const char*)As + aoff[mi][0]);
            float4v y = *(const float4v*)((const char*)As + aoff[mi][1]);
            union { int4v i; short8 s; } u;
            asm("v_cvt_pk_bf16_f32 %0, %1, %2" : "=v"(u.i.x) : "v"(x[0]), "v"(x[1]));
            asm("v_cvt_pk_bf16_f32 %0, %1, %2" : "=v"(u.i.y) : "v"(x[2]), "v"(x[3]));
            asm("v_cvt_pk_bf16_f32 %0, %1, %2" : "=v"(u.i.z) : "v"(y[0]), "v"(y[1]));
            asm("v_cvt_pk_bf16_f32 %0, %1, %2" : "=v"(u.i.w) : "v"(y[2]), "v"(y[3]));
            af[mi] = u.s;
        }
        #pragma unroll
        for (int ni = 0; ni < 4; ++ni)
            bf[ni] = *(const short8*)((const char*)Bs + boff[ni]);

        #pragma unroll
        for (int mi = 0; mi < 4; ++mi)
            #pragma unroll
            for (int ni = 0; ni < 4; ++ni)
                acc[mi][ni] = __builtin_amdgcn_mfma_f32_16x16x32_bf16(af[mi], bf[ni], acc[mi][ni], 0, 0, 0);
        __syncthreads();
    }

    // epilogue: u = tanh(acc + qc), partial logit = sum_n u*v[n], 16-lane reduce, atomicAdd
    const float* qcb = qc + b * 512;
    float vcol[4], qcol[4];
    #pragma unroll
    for (int ni = 0; ni < 4; ++ni) {
        int c = col0 + wn * 64 + ni * 16 + (lane & 15);
        vcol[ni] = v[c];
        qcol[ni] = qcb[c];
    }
    int rbase = wm * 64 + 4 * (lane >> 4);
    #pragma unroll
    for (int mi = 0; mi < 4; ++mi) {
        #pragma unroll
        for (int j = 0; j < 4; ++j) {
            float s = 0.f;
            #pragma unroll
            for (int ni = 0; ni < 4; ++ni) {
                float x = acc[mi][ni][j] + qcol[ni];
                float e2 = __expf(2.0f * x);
                float t = 1.0f - 2.0f * __builtin_amdgcn_rcpf(e2 + 1.0f);
                s += t * vcol[ni];
            }
            s += __shfl_xor(s, 1);
            s += __shfl_xor(s, 2);
            s += __shfl_xor(s, 4);
            s += __shfl_xor(s, 8);
            if ((lane & 15) == 0) {
                atomicAdd(&logits[row0 + rbase + mi * 16 + j], s);
            }
        }
    }
}

// masked softmax per batch row
__global__ void softmax_kernel(const float* __restrict__ logits, const int* __restrict__ length,
                               float* __restrict__ att) {
    int b = blockIdx.x;
    int len = length[b];
    int tid = threadIdx.x;     // 256
    int lane = tid & 63, wv = tid >> 6;
    const float* lg = logits + b * 2048;
    float* ab = att + b * 2048;

    float vals[8];
    float mymax = -3.402823466e38f;
    #pragma unroll
    for (int i = 0; i < 8; ++i) {
        int l = tid + i * 256;
        float x = (l < len) ? lg[l] : NEGV;
        vals[i] = x;
        mymax = fmaxf(mymax, x);
    }
    #pragma unroll
    for (int m = 32; m; m >>= 1) mymax = fmaxf(mymax, __shfl_xor(mymax, m));
    __shared__ float sm[4];
    if (lane == 0) sm[wv] = mymax;
    __syncthreads();
    float bmax = fmaxf(fmaxf(sm[0], sm[1]), fmaxf(sm[2], sm[3]));

    float mysum = 0.f;
    #pragma unroll
    for (int i = 0; i < 8; ++i) {
        int l = tid + i * 256;
        float e = (l < len) ? __expf(vals[i] - bmax) : 0.f;
        vals[i] = e;
        mysum += e;
    }
    #pragma unroll
    for (int m = 32; m; m >>= 1) mysum += __shfl_xor(mysum, m);
    __shared__ float ss[4];
    if (lane == 0) ss[wv] = mysum;
    __syncthreads();
    float tot = ss[0] + ss[1] + ss[2] + ss[3];
    float inv = 1.0f / (tot + 1e-5f);
    #pragma unroll
    for (int i = 0; i < 8; ++i) {
        int l = tid + i * 256;
        ab[l] = vals[i] * inv;
    }
}

// context[b][e] = sum_l att[b][l] * enc[b][l][e]; skip masked L-chunks
__global__ void ctx_kernel(const float* __restrict__ att, const float* __restrict__ enc,
                           const int* __restrict__ length, float* __restrict__ ctx) {
    int b = blockIdx.x;        // 64
    int lc = blockIdx.y;       // 16 chunks of 128
    int len = length[b];
    int l0 = lc * 128;
    if (l0 >= len) return;
    int lim = len - l0;
    if (lim > 128) lim = 128;

    int t = threadIdx.x;       // 256 -> 2 cols each
    const float* ab = att + b * 2048 + l0;
    const float* eb = enc + ((long)(b * 2048 + l0)) * 512 + t * 2;
    float c0 = 0.f, c1 = 0.f;
    #pragma unroll 4
    for (int l = 0; l < lim; ++l) {
        float a = ab[l];
        float2v e = *(const float2v*)(eb);
        eb += 512;
        c0 += a * e.x;
        c1 += a * e.y;
    }
    atomicAdd(&ctx[b * 512 + 2 * t], c0);
    atomicAdd(&ctx[b * 512 + 2 * t + 1], c1);
}

extern "C" void kernel_launch(void* const* d_in, const int* in_sizes, int n_in,
                              void* d_out, int out_size, void* d_ws, size_t ws_size,
                              hipStream_t stream) {
    const float* enc    = (const float*)d_in[0];   // [64,2048,512]
    const float* query  = (const float*)d_in[1];   // [64,256]
    const int*   length = (const int*)d_in[2];     // [64]
    const float* W1     = (const float*)d_in[3];   // [768,512]
    const float* b1     = (const float*)d_in[4];   // [512]
    const float* v      = (const float*)d_in[5];   // [512]

    float* out = (float*)d_out;
    float* ctx = out;                // [64,512]
    float* att = out + 64 * 512;     // [64,2048]

    char* ws = (char*)d_ws;
    float* logits      = (float*)ws;                              // 512KB
    float* qc          = (float*)(ws + 64 * 2048 * 4);            // 128KB
    unsigned short* Wt = (unsigned short*)(ws + 64 * 2048 * 4 + 64 * 512 * 4); // 512KB

    hipMemsetAsync(logits, 0, 64 * 2048 * 4, stream);
    hipMemsetAsync(ctx, 0, 64 * 512 * 4, stream);

    prep_wt_kernel<<<(512 * 512) / 256, 256, 0, stream>>>(W1, Wt);
    prep_qc_kernel<<<64, 256, 0, stream>>>(query, W1, b1, qc);

    gemm_logits_kernel<<<4096, 256, 0, stream>>>(enc, Wt, qc, v, length, logits);

    softmax_kernel<<<64, 256, 0, stream>>>(logits, length, att);

    dim3 g3(64, 16);
    ctx_kernel<<<g3, 256, 0, stream>>>(att, enc, length, ctx);
}

// Round 4
// 146.084 us; speedup vs baseline: 1.3442x; 1.0364x over previous
//
#include <hip/hip_runtime.h>

typedef __attribute__((ext_vector_type(4))) float float4v;
typedef __attribute__((ext_vector_type(2))) float float2v;
typedef __attribute__((ext_vector_type(8))) short short8;
typedef __attribute__((ext_vector_type(4))) float f32x4;
typedef __attribute__((ext_vector_type(4))) int int4v;

#define NEGV (-1000000000.0f)

// B=64, L=2048, E=512, Q=256; M = 131072, K = 512, N = 512
#define MTOT (64 * 2048)

__device__ __forceinline__ unsigned short f2bf(float f) {
    unsigned int u = __float_as_uint(f);
    u += 0x7fffu + ((u >> 16) & 1u);   // RNE round to bf16
    return (unsigned short)(u >> 16);
}

// async global->LDS, 16B per lane, LDS dest = wave-uniform base + lane*16
__device__ __forceinline__ void gload_lds16(const void* g, void* l) {
    __builtin_amdgcn_global_load_lds(
        (__attribute__((address_space(1))) unsigned int*)(unsigned long long)(g),
        (__attribute__((address_space(3))) unsigned int*)(unsigned int)(unsigned long long)(l),
        16, 0, 0);
}

// Wt[e][c] = bf16(W1[c][e]) via LDS 32x32 tile transpose (coalesced both sides).
__global__ __launch_bounds__(256)
void prep_wt_kernel(const float* __restrict__ W1, unsigned short* __restrict__ Wt) {
    __shared__ float t[32][33];
    int bx = blockIdx.x & 15;    // c tile
    int by = blockIdx.x >> 4;    // e tile
    int tx = threadIdx.x & 31;
    int ty = threadIdx.x >> 5;   // 0..7
    #pragma unroll
    for (int i = 0; i < 4; ++i)
        t[ty + 8 * i][tx] = W1[(bx * 32 + ty + 8 * i) * 512 + by * 32 + tx];
    __syncthreads();
    #pragma unroll
    for (int i = 0; i < 4; ++i)
        Wt[(by * 32 + ty + 8 * i) * 512 + bx * 32 + tx] = f2bf(t[tx][ty + 8 * i]);
}

// qc[b][e] = b1[e] + sum_q query[b][q] * W1[512+q][e]
__global__ void prep_qc_kernel(const float* __restrict__ query, const float* __restrict__ W1,
                               const float* __restrict__ b1, float* __restrict__ qc) {
    int b = blockIdx.x;
    int e = threadIdx.x;           // 256 threads -> cols e and e+256
    float acc0 = b1[e];
    float acc1 = b1[e + 256];
    const float* w = W1 + 512 * 512;
    for (int q = 0; q < 256; ++q) {
        float qv = query[b * 256 + q];
        acc0 += qv * w[q * 512 + e];
        acc1 += qv * w[q * 512 + e + 256];
    }
    qc[b * 512 + e] = acc0;
    qc[b * 512 + e + 256] = acc1;
}

// 128x128 tile, BK=32, 4 waves, double-buffered global_load_lds staging,
// XOR-swizzled f32 A tile, 2-phase pipeline (stage next || compute cur).
// Partial logits go to part[bn*2+wn][row]: unique writer per slice, no atomics.
__global__ __launch_bounds__(256)
void gemm_logits_kernel(const float* __restrict__ A,            // encoded [M][512] f32
                        const unsigned short* __restrict__ Wt,  // [512 n][512 k] bf16
                        const float* __restrict__ qc,           // [64][512]
                        const float* __restrict__ v,            // [512]
                        const int* __restrict__ length,         // [64]
                        float* __restrict__ part)               // [8][M] partial logits
{
    // bijective XCD swizzle: 4096 blocks, 8 XCDs, 512 per XCD; the 4 bn-slices
    // of one bm are consecutive origs -> same XCD -> A-tile L2 reuse.
    int bid = blockIdx.x;
    int orig = (bid & 7) * 512 + (bid >> 3);
    int bm = orig >> 2;        // 0..1023 row tile
    int bn = orig & 3;         // 0..3   N slice
    int b = bm >> 4;
    int l0 = (bm & 15) * 128;
    if (l0 >= length[b]) return;   // fully-masked tile

    __shared__ float As[2][128 * 32];           // swizzled: kb ^= (row&7)<<4
    __shared__ unsigned short Bs[2][128 * 32];  // linear

    int tid = threadIdx.x;
    int lane = tid & 63;
    int w = tid >> 6;
    int wm = w >> 1, wn = w & 1;
    long row0 = (long)bm * 128;
    int col0 = bn * 128;

    // staging: LDS linear dest, global pre-swizzled source (m173 pattern)
    const char* gA[4];
    const char* gB[2];
    #pragma unroll
    for (int i = 0; i < 4; ++i) {
        int off = (w * 4 + i) * 1024 + lane * 16;   // linear LDS byte in A-tile
        int r = off >> 7;                            // 128B per row (32 f32)
        int kbg = (off & 127) ^ ((r & 7) << 4);      // inverse swizzle on source
        gA[i] = (const char*)A + (row0 + r) * 2048 + kbg;
    }
    #pragma unroll
    for (int i = 0; i < 2; ++i) {
        int off = (w * 2 + i) * 1024 + lane * 16;   // 64B per row (32 bf16)
        gB[i] = (const char*)Wt + (long)(col0 + (off >> 6)) * 1024 + (off & 63);
    }
    char* lA0 = (char*)&As[0][0] + w * 4096;
    char* lA1 = (char*)&As[1][0] + w * 4096;
    char* lB0 = (char*)&Bs[0][0] + w * 2048;
    char* lB1 = (char*)&Bs[1][0] + w * 2048;

    // fragment read byte offsets (within one buffer)
    int aoff[4][2], boff[4];
    int kb0 = 32 * (lane >> 4);
    #pragma unroll
    for (int mi = 0; mi < 4; ++mi) {
        int ar = wm * 64 + (lane & 15) + mi * 16;
        int swz = (ar & 7) << 4;
        aoff[mi][0] = ar * 128 + (kb0 ^ swz);
        aoff[mi][1] = ar * 128 + ((kb0 + 16) ^ swz);
    }
    int kbB = 16 * (lane >> 4);
    #pragma unroll
    for (int ni = 0; ni < 4; ++ni)
        boff[ni] = (wn * 64 + (lane & 15) + ni * 16) * 64 + kbB;

    f32x4 acc[4][4] = {};

    auto STAGE = [&](int t, char* la, char* lb) {
        gload_lds16(gA[0] + t * 128, la);
        gload_lds16(gA[1] + t * 128, la + 1024);
        gload_lds16(gA[2] + t * 128, la + 2048);
        gload_lds16(gA[3] + t * 128, la + 3072);
        gload_lds16(gB[0] + t * 64, lb);
        gload_lds16(gB[1] + t * 64, lb + 1024);
    };
    auto COMPUTE = [&](const float* as, const unsigned short* bs) {
        short8 af[4], bf[4];
        #pragma unroll
        for (int mi = 0; mi < 4; ++mi) {
            float4v x = *(const float4v*)((const char*)as + aoff[mi][0]);
            float4v y = *(const float4v*)((const char*)as + aoff[mi][1]);
            union { int4v i; short8 s; } u;
            asm("v_cvt_pk_bf16_f32 %0, %1, %2" : "=v"(u.i.x) : "v"(x[0]), "v"(x[1]));
            asm("v_cvt_pk_bf16_f32 %0, %1, %2" : "=v"(u.i.y) : "v"(x[2]), "v"(x[3]));
            asm("v_cvt_pk_bf16_f32 %0, %1, %2" : "=v"(u.i.z) : "v"(y[0]), "v"(y[1]));
            asm("v_cvt_pk_bf16_f32 %0, %1, %2" : "=v"(u.i.w) : "v"(y[2]), "v"(y[3]));
            af[mi] = u.s;
        }
        #pragma unroll
        for (int ni = 0; ni < 4; ++ni)
            bf[ni] = *(const short8*)((const char*)bs + boff[ni]);
        #pragma unroll
        for (int mi = 0; mi < 4; ++mi)
            #pragma unroll
            for (int ni = 0; ni < 4; ++ni)
                acc[mi][ni] = __builtin_amdgcn_mfma_f32_16x16x32_bf16(af[mi], bf[ni], acc[mi][ni], 0, 0, 0);
    };

    STAGE(0, lA0, lB0);
    __syncthreads();
    #pragma unroll 1
    for (int ks = 0; ks < 16; ks += 2) {
        STAGE(ks + 1, lA1, lB1);          // into buf1 while computing buf0
        COMPUTE(&As[0][0], &Bs[0][0]);
        __syncthreads();                  // drains vmcnt(0): buf1 ready
        if (ks + 2 < 16) STAGE(ks + 2, lA0, lB0);
        COMPUTE(&As[1][0], &Bs[1][0]);
        __syncthreads();
    }

    // epilogue: u = tanh(acc + qc), partial logit = sum over this wave's 64
    // cols of u*v, 16-lane reduce, store into this (bn,wn) slice.
    const float* qcb = qc + b * 512;
    float vcol[4], qcol[4];
    #pragma unroll
    for (int ni = 0; ni < 4; ++ni) {
        int c = col0 + wn * 64 + ni * 16 + (lane & 15);
        vcol[ni] = v[c];
        qcol[ni] = qcb[c];
    }
    float* pslice = part + (bn * 2 + wn) * MTOT + row0;   // unique writer slice
    int rbase = wm * 64 + 4 * (lane >> 4);
    #pragma unroll
    for (int mi = 0; mi < 4; ++mi) {
        #pragma unroll
        for (int j = 0; j < 4; ++j) {
            float s = 0.f;
            #pragma unroll
            for (int ni = 0; ni < 4; ++ni) {
                float x = acc[mi][ni][j] + qcol[ni];
                float e2 = __expf(2.0f * x);
                float t = 1.0f - 2.0f * __builtin_amdgcn_rcpf(e2 + 1.0f);
                s += t * vcol[ni];
            }
            s += __shfl_xor(s, 1);
            s += __shfl_xor(s, 2);
            s += __shfl_xor(s, 4);
            s += __shfl_xor(s, 8);
            if ((lane & 15) == 0)
                pslice[rbase + mi * 16 + j] = s;
        }
    }
}

// masked softmax per batch row; sums 8 (bn,wn) partials; also zeroes ctx[b]
__global__ void softmax_kernel(const float* __restrict__ part, const int* __restrict__ length,
                               float* __restrict__ att, float* __restrict__ ctx) {
    int b = blockIdx.x;
    int len = length[b];
    int tid = threadIdx.x;     // 256
    int lane = tid & 63, wv = tid >> 6;
    const float* p0 = part + b * 2048;
    float* ab = att + b * 2048;

    ctx[b * 512 + tid] = 0.f;              // zero context (ctx_kernel atomicAdds)
    ctx[b * 512 + 256 + tid] = 0.f;

    float vals[8];
    float mymax = -3.402823466e38f;
    #pragma unroll
    for (int i = 0; i < 8; ++i) {
        int l = tid + i * 256;
        float x = NEGV;
        if (l < len) {
            x = 0.f;
            #pragma unroll
            for (int s = 0; s < 8; ++s)
                x += p0[s * MTOT + l];
        }
        vals[i] = x;
        mymax = fmaxf(mymax, x);
    }
    #pragma unroll
    for (int m = 32; m; m >>= 1) mymax = fmaxf(mymax, __shfl_xor(mymax, m));
    __shared__ float sm[4];
    if (lane == 0) sm[wv] = mymax;
    __syncthreads();
    float bmax = fmaxf(fmaxf(sm[0], sm[1]), fmaxf(sm[2], sm[3]));

    float mysum = 0.f;
    #pragma unroll
    for (int i = 0; i < 8; ++i) {
        int l = tid + i * 256;
        float e = (l < len) ? __expf(vals[i] - bmax) : 0.f;
        vals[i] = e;
        mysum += e;
    }
    #pragma unroll
    for (int m = 32; m; m >>= 1) mysum += __shfl_xor(mysum, m);
    __shared__ float ss[4];
    if (lane == 0) ss[wv] = mysum;
    __syncthreads();
    float tot = ss[0] + ss[1] + ss[2] + ss[3];
    float inv = 1.0f / (tot + 1e-5f);
    #pragma unroll
    for (int i = 0; i < 8; ++i) {
        int l = tid + i * 256;
        ab[l] = vals[i] * inv;
    }
}

// context[b][e] = sum_l att[b][l] * enc[b][l][e]; skip masked L-chunks
__global__ void ctx_kernel(const float* __restrict__ att, const float* __restrict__ enc,
                           const int* __restrict__ length, float* __restrict__ ctx) {
    int b = blockIdx.x;        // 64
    int lc = blockIdx.y;       // 16 chunks of 128
    int len = length[b];
    int l0 = lc * 128;
    if (l0 >= len) return;
    int lim = len - l0;
    if (lim > 128) lim = 128;

    int t = threadIdx.x;       // 256 -> 2 cols each
    const float* ab = att + b * 2048 + l0;
    const float* eb = enc + ((long)(b * 2048 + l0)) * 512 + t * 2;
    float c0 = 0.f, c1 = 0.f;
    #pragma unroll 4
    for (int l = 0; l < lim; ++l) {
        float a = ab[l];
        float2v e = *(const float2v*)(eb);
        eb += 512;
        c0 += a * e.x;
        c1 += a * e.y;
    }
    atomicAdd(&ctx[b * 512 + 2 * t], c0);
    atomicAdd(&ctx[b * 512 + 2 * t + 1], c1);
}

extern "C" void kernel_launch(void* const* d_in, const int* in_sizes, int n_in,
                              void* d_out, int out_size, void* d_ws, size_t ws_size,
                              hipStream_t stream) {
    const float* enc    = (const float*)d_in[0];   // [64,2048,512]
    const float* query  = (const float*)d_in[1];   // [64,256]
    const int*   length = (const int*)d_in[2];     // [64]
    const float* W1     = (const float*)d_in[3];   // [768,512]
    const float* b1     = (const float*)d_in[4];   // [512]
    const float* v      = (const float*)d_in[5];   // [512]

    float* out = (float*)d_out;
    float* ctx = out;                // [64,512]
    float* att = out + 64 * 512;     // [64,2048]

    char* ws = (char*)d_ws;
    float* part        = (float*)ws;                               // 8*M f32 = 4MB
    float* qc          = (float*)(ws + 8 * MTOT * 4);              // 128KB
    unsigned short* Wt = (unsigned short*)(ws + 8 * MTOT * 4 + 64 * 512 * 4); // 512KB

    prep_wt_kernel<<<256, 256, 0, stream>>>(W1, Wt);
    prep_qc_kernel<<<64, 256, 0, stream>>>(query, W1, b1, qc);

    gemm_logits_kernel<<<4096, 256, 0, stream>>>(enc, Wt, qc, v, length, part);

    softmax_kernel<<<64, 256, 0, stream>>>(part, length, att, ctx);

    dim3 g3(64, 16);
    ctx_kernel<<<g3, 256, 0, stream>>>(att, enc, length, ctx);
}